// Round 1
// baseline (1415.833 us; speedup 1.0000x reference)
//
#include <hip/hip_runtime.h>
#include <math.h>

#define BB 8
#define TT 16
#define SS 400
#define HH 512
#define EE 128
#define VV 50000
#define VE 50050
#define OOVn 50

// output offsets (floats)
#define O1 6406400
#define O2 6410496
#define O3 6414592
#define O4 6418688
#define O5 6469888
#define O6 6469896

typedef __attribute__((ext_vector_type(4))) float floatx4;
typedef __attribute__((ext_vector_type(8))) short short8;

__device__ __forceinline__ float sigm(float x){ return 1.0f/(1.0f+__expf(-x)); }

__device__ __forceinline__ unsigned short f2bf(float f){
  union { float f; unsigned int u; } v; v.f = f;
  unsigned int u = v.u;
  return (unsigned short)((u + 0x7FFFu + ((u >> 16) & 1u)) >> 16);
}

// C[M,N] = A[M,K] @ B[N,K]^T (+bias), fp32 in, bf16 MFMA, fp32 out.
// M = gridDim.x*128 (exact), N may be ragged (guarded). K multiple of 64.
// permute: C row for logical row m is (m&7)*16 + (m>>3)   (m = t*8+b -> b*16+t)
__global__ __launch_bounds__(256)
void gemm_bt(const float* __restrict__ A, int lda,
             const float* __restrict__ Bm, int ldb,
             const float* __restrict__ bias,
             float* __restrict__ Cm, int ldc,
             int N, int K, int permute)
{
  __shared__ unsigned short Ash[128*72];
  __shared__ unsigned short Bsh[128*72];
  int tid = threadIdx.x;
  int mbase = blockIdx.x * 128;
  int nbase = blockIdx.y * 128;
  int wave = tid >> 6, lane = tid & 63;
  int wm = (wave & 1) * 64, wn = (wave >> 1) * 64;
  int fl = lane & 15, quad = lane >> 4;

  floatx4 acc[4][4];
  for (int i=0;i<4;i++) for(int j=0;j<4;j++) acc[i][j] = (floatx4)(0.0f);

  for (int kc = 0; kc < K; kc += 64) {
    for (int i = 0; i < 8; ++i) {
      int idx = tid + i*256;
      int row = idx >> 4;
      int c4 = (idx & 15) << 2;
      const float4 vA = *(const float4*)(A + (size_t)(mbase+row)*lda + kc + c4);
      int o = row*72 + c4;
      Ash[o+0]=f2bf(vA.x); Ash[o+1]=f2bf(vA.y); Ash[o+2]=f2bf(vA.z); Ash[o+3]=f2bf(vA.w);
    }
    for (int i = 0; i < 8; ++i) {
      int idx = tid + i*256;
      int row = idx >> 4;
      int c4 = (idx & 15) << 2;
      int gn = nbase + row;
      int o = row*72 + c4;
      if (gn < N) {
        const float4 vB = *(const float4*)(Bm + (size_t)gn*ldb + kc + c4);
        Bsh[o+0]=f2bf(vB.x); Bsh[o+1]=f2bf(vB.y); Bsh[o+2]=f2bf(vB.z); Bsh[o+3]=f2bf(vB.w);
      } else {
        Bsh[o+0]=0; Bsh[o+1]=0; Bsh[o+2]=0; Bsh[o+3]=0;
      }
    }
    __syncthreads();
    for (int ks = 0; ks < 2; ++ks) {
      short8 af[4], bf[4];
      int ko = ks*32 + quad*8;
      for (int i=0;i<4;i++) af[i] = *(const short8*)&Ash[(wm + i*16 + fl)*72 + ko];
      for (int j=0;j<4;j++) bf[j] = *(const short8*)&Bsh[(wn + j*16 + fl)*72 + ko];
      for (int i=0;i<4;i++)
        for (int j=0;j<4;j++)
          acc[i][j] = __builtin_amdgcn_mfma_f32_16x16x32_bf16(af[i], bf[j], acc[i][j], 0,0,0);
    }
    __syncthreads();
  }
  for (int i=0;i<4;i++){
    for (int j=0;j<4;j++){
      int nc = nbase + wn + j*16 + fl;
      if (nc >= N) continue;
      float bv = bias ? bias[nc] : 0.0f;
      for (int r=0;r<4;r++){
        int mg = mbase + wm + i*16 + quad*4 + r;
        int orow = permute ? ((mg & 7)*16 + (mg >> 3)) : mg;
        Cm[(size_t)orow*ldc + nc] = acc[i][j][r] + bv;
      }
    }
  }
}

// x[b,e] = [emb_t(b) ; ctx_{t-1}(b)] @ xctx_w[e,:] + xctx_b[e]
__global__ void k_x(const float* __restrict__ emb, const float* __restrict__ context,
                    const float* __restrict__ A1, const float* __restrict__ xw,
                    const float* __restrict__ xb, float* __restrict__ xall, int t)
{
  int b = blockIdx.x, e = threadIdx.x; // 8 x 128
  __shared__ float in[640];
  const float* ctxp = (t==0) ? (context + b*512) : (A1 + ((size_t)((t-1)*8+b))*1024 + 512);
  if (e < 128) in[e] = emb[(size_t)(b*TT + t)*EE + e];
  for (int i = e; i < 512; i += 128) in[128+i] = ctxp[i];
  __syncthreads();
  const float* w = xw + (size_t)e*640;
  float a0 = xb[e], a1 = 0.0f;
  for (int k = 0; k < 640; k += 4) {
    float4 wv = *(const float4*)(w + k);
    a0 += wv.x*in[k]   + wv.y*in[k+1];
    a1 += wv.z*in[k+2] + wv.w*in[k+3];
  }
  xall[(size_t)(t*8+b)*EE + e] = a0 + a1;
}

// gates[r,b] = b_ih[r]+b_hh[r] + x[b]@W_ih[r] + h_{t-1}[b]@W_hh[r]
__global__ __launch_bounds__(256) void k_gates(
  const float* __restrict__ xall, const float* __restrict__ h0,
  const float* __restrict__ A1,
  const float* __restrict__ wih, const float* __restrict__ whh,
  const float* __restrict__ bih, const float* __restrict__ bhh,
  float* __restrict__ gates, int t)
{
  __shared__ float xl[8][132];
  __shared__ float hl[8][516];
  int tid = threadIdx.x;
  int r = blockIdx.x*32 + (tid >> 3);
  int b = tid & 7;
  for (int i = tid; i < 1024; i += 256) { int b2=i>>7, k=i&127; xl[b2][k] = xall[(size_t)(t*8+b2)*EE + k]; }
  for (int i = tid; i < 4096; i += 256) {
    int b2 = i >> 9, k = i & 511;
    hl[b2][k] = (t==0) ? h0[b2*HH + k] : A1[((size_t)((t-1)*8+b2))*1024 + k];
  }
  __syncthreads();
  float a0 = bih[r] + bhh[r], a1 = 0.0f;
  const float* wi = wih + (size_t)r*128;
  for (int k = 0; k < 128; k += 4) {
    float4 w4 = *(const float4*)(wi + k);
    a0 += w4.x*xl[b][k]   + w4.y*xl[b][k+1];
    a1 += w4.z*xl[b][k+2] + w4.w*xl[b][k+3];
  }
  const float* wh = whh + (size_t)r*512;
  for (int k = 0; k < 512; k += 4) {
    float4 w4 = *(const float4*)(wh + k);
    a0 += w4.x*hl[b][k]   + w4.y*hl[b][k+1];
    a1 += w4.z*hl[b][k+2] + w4.w*hl[b][k+3];
  }
  gates[r*8 + b] = a0 + a1;
}

// LSTM cell update; writes h to A1[t] cols 0..511, zeroes ctx cols 512..1023
__global__ void k_hc(const float* __restrict__ gates, const float* __restrict__ c0,
                     float* __restrict__ wsc, float* __restrict__ A1, int t)
{
  int g = blockIdx.x*256 + threadIdx.x; // 4096
  int b = g >> 9, j = g & 511;
  float gi = gates[j*8 + b];
  float gf = gates[(512+j)*8 + b];
  float gg = gates[(1024+j)*8 + b];
  float go = gates[(1536+j)*8 + b];
  float cp = (t==0) ? c0[b*HH+j] : wsc[b*HH+j];
  float cn = sigm(gf)*cp + sigm(gi)*tanhf(gg);
  float hn = sigm(go)*tanhf(cn);
  wsc[b*HH+j] = cn;
  size_t rowo = ((size_t)(t*8+b))*1024;
  A1[rowo + j] = hn;
  A1[rowo + 512 + j] = 0.0f;
}

// hp[b,p] = energy_b[p] + h_t[b] @ energy_w[p, 0:512]
__global__ __launch_bounds__(256) void k_hproj(const float* __restrict__ A1,
                       const float* __restrict__ ew, const float* __restrict__ eb,
                       float* __restrict__ hp, int t)
{
  __shared__ float hl[8][516];
  int tid = threadIdx.x;
  int p = blockIdx.x*32 + (tid >> 3);
  int b = tid & 7;
  for (int i = tid; i < 4096; i += 256) {
    int b2 = i >> 9, k = i & 511;
    hl[b2][k] = A1[((size_t)(t*8+b2))*1024 + k];
  }
  __syncthreads();
  const float* w = ew + (size_t)p*1024;
  float a0 = eb[p], a1 = 0.0f;
  for (int k = 0; k < 512; k += 4) {
    float4 w4 = *(const float4*)(w + k);
    a0 += w4.x*hl[b][k]   + w4.y*hl[b][k+1];
    a1 += w4.z*hl[b][k+2] + w4.w*hl[b][k+3];
  }
  hp[b*HH + p] = a0 + a1;
}

// e[b,s] = sum_h tanh(hp[b,h] + enc_proj[b,s,h] + cov[b,s]*cov_w[h]) * v[h]
__global__ __launch_bounds__(256) void k_e(const float* __restrict__ encp,
                   const float* __restrict__ hp, const float* __restrict__ vvec,
                   const float* __restrict__ covw, const float* __restrict__ coverage,
                   const float* __restrict__ out6, float* __restrict__ evec, int t)
{
  __shared__ float hpl[512], vl[512], cwl[512];
  int b = blockIdx.y;
  int tid = threadIdx.x;
  for (int i = tid; i < 512; i += 256) {
    hpl[i] = hp[b*HH + i];
    vl[i] = vvec[i];
    cwl[i] = covw[i];
  }
  __syncthreads();
  int wave = tid >> 6, lane = tid & 63;
  int s0 = blockIdx.x*16 + wave*4;
  const float* covp = (t==0) ? (coverage + b*SS) : (out6 + ((size_t)(b*TT + t-1))*SS);
  for (int q = 0; q < 4; ++q) {
    int s = s0 + q;
    float cv = covp[s];
    const float* ep = encp + ((size_t)(b*SS + s))*HH;
    float acc = 0.0f;
    for (int k = 0; k < 2; ++k) {
      int h = k*256 + lane*4;
      float4 epv = *(const float4*)(ep + h);
      float4 hpv = *(const float4*)&hpl[h];
      float4 vv  = *(const float4*)&vl[h];
      float4 cwv = *(const float4*)&cwl[h];
      acc += tanhf(hpv.x + epv.x + cv*cwv.x)*vv.x;
      acc += tanhf(hpv.y + epv.y + cv*cwv.y)*vv.y;
      acc += tanhf(hpv.z + epv.z + cv*cwv.z)*vv.z;
      acc += tanhf(hpv.w + epv.w + cv*cwv.w)*vv.w;
    }
    for (int off = 32; off > 0; off >>= 1) acc += __shfl_down(acc, off);
    if (lane == 0) evec[b*SS + s] = acc;
  }
}

// softmax over S with mask renorm; probs -> out4, cov_new -> out6
__global__ __launch_bounds__(512) void k_soft(const float* __restrict__ evec,
                     const float* __restrict__ masks, const float* __restrict__ coverage,
                     float* __restrict__ out4, float* __restrict__ out6, int t)
{
  int b = blockIdx.x;
  int tid = threadIdx.x;
  __shared__ float red[16];
  __shared__ float smx, sd1, sd2;
  int s = tid;
  bool ok = s < SS;
  float ev = ok ? evec[b*SS + s] : -1e30f;
  float mx = ev;
  for (int off=32; off>0; off>>=1) mx = fmaxf(mx, __shfl_down(mx, off));
  int wave = tid >> 6, lane = tid & 63;
  if (lane==0) red[wave] = mx;
  __syncthreads();
  if (tid==0){ float m2=red[0]; for(int i=1;i<8;i++) m2=fmaxf(m2,red[i]); smx=m2; }
  __syncthreads();
  float p1 = ok ? __expf(ev - smx) : 0.0f;
  float mk = ok ? masks[b*SS + s] : 0.0f;
  float pm = p1*mk;
  float a1 = p1, a2 = pm;
  for (int off=32; off>0; off>>=1) { a1 += __shfl_down(a1,off); a2 += __shfl_down(a2,off); }
  if (lane==0){ red[wave] = a1; red[8+wave] = a2; }
  __syncthreads();
  if (tid==0){ float d1=0,d2=0; for(int i=0;i<8;i++){d1+=red[i]; d2+=red[8+i];} sd1=d1; sd2=d2; }
  __syncthreads();
  if (ok) {
    float pr = pm / (sd2 + 1e-12f*sd1);
    size_t o = ((size_t)(b*TT + t))*SS + s;
    out4[o] = pr;
    float cv = (t==0) ? coverage[b*SS+s] : out6[((size_t)(b*TT + t-1))*SS + s];
    out6[o] = cv + pr;
  }
}

// ctx_t[b,c] += sum_{s in chunk} probs[b,s]*enc[b,s,c]  (into A1 cols 512..1023)
__global__ void k_ctx(const float* __restrict__ out4, const float* __restrict__ enc,
                      float* __restrict__ A1, int t)
{
  int cc = blockIdx.x, b = blockIdx.y, sc = blockIdx.z; // (4, 8, 5), 128 thr
  int c = cc*128 + threadIdx.x;
  __shared__ float pl[80];
  int tid = threadIdx.x;
  const float* pr = out4 + ((size_t)(b*TT + t))*SS + sc*80;
  if (tid < 80) pl[tid] = pr[tid];
  __syncthreads();
  float acc = 0.0f;
  const float* ep = enc + ((size_t)(b*SS + sc*80))*512 + c;
  for (int s = 0; s < 80; ++s) acc += pl[s]*ep[(size_t)s*512];
  atomicAdd(&A1[((size_t)(t*8+b))*1024 + 512 + c], acc);
}

// final h/c/ctx copies
__global__ void k_finish(const float* __restrict__ A1, const float* __restrict__ wsc,
                         float* __restrict__ out)
{
  int g = blockIdx.x*256 + threadIdx.x; // 12288
  int which = g >> 12;
  int i = g & 4095;
  int b = i >> 9, j = i & 511;
  if (which == 0)      out[O1 + i] = A1[((size_t)(15*8+b))*1024 + 512 + j];
  else if (which == 1) out[O2 + i] = A1[((size_t)(15*8+b))*1024 + j];
  else                 out[O3 + i] = wsc[i];
}

// p_gen for all (t,b)
__global__ void k_pgen(const float* __restrict__ A1, const float* __restrict__ xall,
                       const float* __restrict__ pw, const float* __restrict__ pb,
                       float* __restrict__ pgen, float* __restrict__ out)
{
  int m = threadIdx.x; // 128
  const float* hrow = A1 + (size_t)m*1024;
  float a0 = pb[0], a1 = 0.0f, a2 = 0.0f, a3 = 0.0f;
  for (int k = 0; k < 512; k += 4) {
    a0 += pw[k]*hrow[512+k];     a1 += pw[k+1]*hrow[512+k+1];
    a2 += pw[k+2]*hrow[512+k+2]; a3 += pw[k+3]*hrow[512+k+3];
  }
  for (int k = 0; k < 512; k += 4) {
    a0 += pw[512+k]*hrow[k];     a1 += pw[512+k+1]*hrow[k+1];
    a2 += pw[512+k+2]*hrow[k+2]; a3 += pw[512+k+3]*hrow[k+3];
  }
  const float* xr = xall + (size_t)m*EE;
  for (int k = 0; k < 128; k += 4) {
    a0 += pw[1024+k]*xr[k];     a1 += pw[1024+k+1]*xr[k+1];
    a2 += pw[1024+k+2]*xr[k+2]; a3 += pw[1024+k+3]*xr[k+3];
  }
  float pg = sigm(a0+a1+a2+a3);
  pgen[m] = pg;
  if ((m >> 3) == 15) out[O5 + (m & 7)] = pg;
}

// in-place vocab softmax on logits rows + p_gen scale + OOV zeros + copy scatter
__global__ __launch_bounds__(256) void k_final(
  float* __restrict__ out, const float* __restrict__ pgen,
  const float* __restrict__ ez, const int* __restrict__ extidx)
{
  int m = blockIdx.x;           // m = t*8+b
  int b = m & 7, t = m >> 3;
  float* row = out + ((size_t)(b*TT + t))*VE;
  int tid = threadIdx.x;
  __shared__ float red[4];
  __shared__ float smx, ssum;
  float mx = -1e30f;
  for (int v2 = tid; v2 < VV; v2 += 256) mx = fmaxf(mx, row[v2]);
  for (int off=32; off>0; off>>=1) mx = fmaxf(mx, __shfl_down(mx, off));
  int wave = tid>>6, lane = tid&63;
  if (lane==0) red[wave] = mx;
  __syncthreads();
  if (tid==0){ float m2=red[0]; for(int i=1;i<4;i++) m2=fmaxf(m2,red[i]); smx=m2; }
  __syncthreads();
  float mxv = smx;
  float sm = 0.0f;
  for (int v2 = tid; v2 < VV; v2 += 256) {
    float e2 = __expf(row[v2] - mxv);
    row[v2] = e2;
    sm += e2;
  }
  for (int off=32; off>0; off>>=1) sm += __shfl_down(sm, off);
  if (lane==0) red[wave] = sm;
  __syncthreads();
  if (tid==0){ float s2=0; for(int i=0;i<4;i++) s2+=red[i]; ssum=s2; }
  __syncthreads();
  float pg = pgen[m];
  float scale = pg / ssum;
  for (int v2 = tid; v2 < VV; v2 += 256) row[v2] *= scale;
  for (int v2 = VV + tid; v2 < VE; v2 += 256) row[v2] = ez[b*OOVn + (v2-VV)];
  __syncthreads();
  float onem = 1.0f - pg;
  const float* pr = out + O4 + ((size_t)(b*TT+t))*SS;
  for (int s2 = tid; s2 < SS; s2 += 256) {
    int ix = extidx[b*SS + s2];
    atomicAdd(&row[ix], onem * pr[s2]);
  }
}

extern "C" void kernel_launch(void* const* d_in, const int* in_sizes, int n_in,
                              void* d_out, int out_size, void* d_ws, size_t ws_size,
                              hipStream_t stream)
{
  (void)in_sizes; (void)n_in; (void)out_size; (void)ws_size;
  const float* emb      = (const float*)d_in[0];
  const float* context  = (const float*)d_in[1];
  const float* h0       = (const float*)d_in[2];
  const float* c0       = (const float*)d_in[3];
  const float* enc      = (const float*)d_in[4];
  const float* masks    = (const float*)d_in[5];
  const float* ez       = (const float*)d_in[6];
  const int*   extidx   = (const int*)d_in[7];
  const float* coverage = (const float*)d_in[8];
  const float* wih      = (const float*)d_in[9];
  const float* whh      = (const float*)d_in[10];
  const float* bih      = (const float*)d_in[11];
  const float* bhh      = (const float*)d_in[12];
  const float* covw     = (const float*)d_in[13];
  const float* ew       = (const float*)d_in[14];
  const float* eb       = (const float*)d_in[15];
  const float* vvec     = (const float*)d_in[16];
  const float* xw       = (const float*)d_in[17];
  const float* xb       = (const float*)d_in[18];
  const float* aw       = (const float*)d_in[19];
  const float* ab       = (const float*)d_in[20];
  const float* vw       = (const float*)d_in[21];
  const float* vb       = (const float*)d_in[22];
  const float* pw       = (const float*)d_in[23];
  const float* pb       = (const float*)d_in[24];
  float* out = (float*)d_out;

  float* ws = (float*)d_ws;
  float* A1         = ws;                    // 128 x 1024 : [h | ctx] per (t,b)
  float* xall       = A1 + 131072;           // 128 x 128
  float* wsc        = xall + 16384;          // 8 x 512  (c state)
  float* gates      = wsc + 4096;            // 2048 x 8
  float* hp         = gates + 16384;         // 8 x 512
  float* evec       = hp + 4096;             // 8 x 400
  float* attnd_feat = evec + 3200;           // 128 x 512
  float* pgen       = attnd_feat + 65536;    // 128
  float* enc_proj   = out;                   // 3200 x 512, borrows out0 region (free until logits GEMM)

  // enc_proj = enc @ energy_w[:,512:].T   (time-invariant part of attention energy)
  gemm_bt<<<dim3(25,4), 256, 0, stream>>>(enc, 512, ew + 512, 1024,
                                          (const float*)nullptr, enc_proj, 512, 512, 512, 0);

  for (int t = 0; t < TT; ++t) {
    k_x<<<8, 128, 0, stream>>>(emb, context, A1, xw, xb, xall, t);
    k_gates<<<64, 256, 0, stream>>>(xall, h0, A1, wih, whh, bih, bhh, gates, t);
    k_hc<<<16, 256, 0, stream>>>(gates, c0, wsc, A1, t);
    k_hproj<<<16, 256, 0, stream>>>(A1, ew, eb, hp, t);
    k_e<<<dim3(25,8), 256, 0, stream>>>(enc_proj, hp, vvec, covw, coverage, out + O6, evec, t);
    k_soft<<<8, 512, 0, stream>>>(evec, masks, coverage, out + O4, out + O6, t);
    k_ctx<<<dim3(4,8,5), 128, 0, stream>>>(out + O4, enc, A1, t);
  }

  k_finish<<<48, 256, 0, stream>>>(A1, wsc, out);
  k_pgen<<<1, 128, 0, stream>>>(A1, xall, pw, pb, pgen, out);
  // attnd_feat = [h|ctx] @ attnd_w.T + attnd_b
  gemm_bt<<<dim3(1,4), 256, 0, stream>>>(A1, 1024, aw, 1024, ab, attnd_feat, 512, 512, 1024, 0);
  // logits (all 16 steps batched) = attnd_feat @ vocab_w.T + vocab_b  -> out0 rows (b*16+t)
  gemm_bt<<<dim3(1,391), 256, 0, stream>>>(attnd_feat, 512, vw, 512, vb, out, VE, VV, 512, 1);
  k_final<<<128, 256, 0, stream>>>(out, pgen, ez, extidx);
}